// Round 1
// baseline (371.374 us; speedup 1.0000x reference)
//
#include <hip/hip_runtime.h>
#include <math.h>

#define N_NODES 50000
#define F_IN 128
#define NE 800000
#define NH1 8
#define ND1 16
#define ND2 8
#define NEG 0.2f

__device__ __forceinline__ float lrelu(float v) { return v > 0.f ? v : NEG * v; }
__device__ __forceinline__ float elu1(float v)  { return v > 0.f ? v : (__expf(v) - 1.f); }

// ---------------- edge dtype detection (int32 vs int64) ----------------
__global__ void detect_kernel(const int* __restrict__ ei, int* __restrict__ flag) {
    if (blockIdx.x == 0 && threadIdx.x == 0) {
        int all0 = 1;
        for (int k = 0; k < 64; ++k) {
            if (ei[2 * k + 1] != 0) { all0 = 0; break; }
        }
        *flag = all0;   // 1 => data is int64 (high words zero), 0 => int32
    }
}

// ---------------- CSR build ----------------
__global__ void init_counts_kernel(int* __restrict__ counts) {
    int i = blockIdx.x * blockDim.x + threadIdx.x;
    if (i < N_NODES) counts[i] = 1;   // self-loop
}

__global__ void hist_kernel(const int* __restrict__ ei, const int* __restrict__ flag,
                            int* __restrict__ counts) {
    int e = blockIdx.x * blockDim.x + threadIdx.x;
    if (e >= NE) return;
    int is64 = *flag;
    int d = is64 ? ei[2 * NE + 2 * e] : ei[NE + e];
    atomicAdd(&counts[d], 1);
}

__global__ __launch_bounds__(1024) void scan_kernel(const int* __restrict__ counts,
                                                    int* __restrict__ rowptr,
                                                    int* __restrict__ cursor) {
    __shared__ int wsum[16];
    __shared__ int wpre[16];
    __shared__ int s_total;
    const int t = threadIdx.x;
    const int lane = t & 63, w = t >> 6;
    int carry = 0;
    if (t == 0) rowptr[0] = 0;
    for (int base = 0; base < N_NODES; base += 1024) {
        int i = base + t;
        int orig = (i < N_NODES) ? counts[i] : 0;
        int v = orig;
        #pragma unroll
        for (int off = 1; off < 64; off <<= 1) {
            int u = __shfl_up(v, off, 64);
            if (lane >= off) v += u;
        }
        if (lane == 63) wsum[w] = v;
        __syncthreads();
        if (t == 0) {
            int s = 0;
            #pragma unroll
            for (int j = 0; j < 16; ++j) { wpre[j] = s; s += wsum[j]; }
            s_total = s;
        }
        __syncthreads();
        int incl = v + wpre[w] + carry;
        if (i < N_NODES) { rowptr[i + 1] = incl; cursor[i] = incl - orig; }
        carry += s_total;
        __syncthreads();
    }
}

__global__ void fill_kernel(const int* __restrict__ ei, const int* __restrict__ flag,
                            int* __restrict__ cursor, int* __restrict__ esrc) {
    int i = blockIdx.x * blockDim.x + threadIdx.x;
    if (i >= NE + N_NODES) return;
    int is64 = *flag;
    int s, d;
    if (i < NE) {
        if (is64) { s = ei[2 * i]; d = ei[2 * NE + 2 * i]; }
        else      { s = ei[i];     d = ei[NE + i]; }
    } else {
        s = d = i - NE;
    }
    int slot = atomicAdd(&cursor[d], 1);
    esrc[slot] = s;
}

// ---------------- conv1 GEMM: h1 = x @ W1  (50000x128 @ 128x128) ----------------
__global__ __launch_bounds__(256) void gemm1_kernel(const float* __restrict__ x,
                                                    const float* __restrict__ W,
                                                    float* __restrict__ h1) {
    __shared__ float Ws[32 * 128];
    __shared__ float Xs[32 * 68];   // transposed x chunk, stride 68 (16B-aligned rows)
    const int t = threadIdx.x;
    const int cg = t & 31;          // col group -> cols cg*4..+3
    const int rg = t >> 5;          // row group -> rows rg*8..+7
    const int row0 = blockIdx.x * 64;

    float acc[8][4];
    #pragma unroll
    for (int i = 0; i < 8; ++i)
        #pragma unroll
        for (int j = 0; j < 4; ++j) acc[i][j] = 0.f;

    for (int kc = 0; kc < 4; ++kc) {
        // stage W chunk (32 x 128)
        #pragma unroll
        for (int i = 0; i < 4; ++i) {
            int fidx = i * 256 + t;
            const float4 wv = *reinterpret_cast<const float4*>(W + kc * 32 * 128 + fidx * 4);
            *reinterpret_cast<float4*>(&Ws[fidx * 4]) = wv;
        }
        // stage x chunk transposed: Xs[kk][r] = x[row0+r][kc*32+kk]
        {
            int r = t >> 2;
            int k4a = t & 3;
            int grow = row0 + r;
            #pragma unroll
            for (int p = 0; p < 2; ++p) {
                int k4 = k4a + p * 4;
                float4 xv = make_float4(0.f, 0.f, 0.f, 0.f);
                if (grow < N_NODES)
                    xv = *reinterpret_cast<const float4*>(x + grow * F_IN + kc * 32 + k4 * 4);
                Xs[(k4 * 4 + 0) * 68 + r] = xv.x;
                Xs[(k4 * 4 + 1) * 68 + r] = xv.y;
                Xs[(k4 * 4 + 2) * 68 + r] = xv.z;
                Xs[(k4 * 4 + 3) * 68 + r] = xv.w;
            }
        }
        __syncthreads();
        #pragma unroll
        for (int kk = 0; kk < 32; ++kk) {
            float4 wv = *reinterpret_cast<const float4*>(&Ws[kk * 128 + cg * 4]);
            float4 xa = *reinterpret_cast<const float4*>(&Xs[kk * 68 + rg * 8]);
            float4 xb = *reinterpret_cast<const float4*>(&Xs[kk * 68 + rg * 8 + 4]);
            float xr[8] = {xa.x, xa.y, xa.z, xa.w, xb.x, xb.y, xb.z, xb.w};
            float wr[4] = {wv.x, wv.y, wv.z, wv.w};
            #pragma unroll
            for (int i = 0; i < 8; ++i)
                #pragma unroll
                for (int j = 0; j < 4; ++j)
                    acc[i][j] = fmaf(xr[i], wr[j], acc[i][j]);
        }
        __syncthreads();
    }
    #pragma unroll
    for (int i = 0; i < 8; ++i) {
        int grow = row0 + rg * 8 + i;
        if (grow < N_NODES) {
            float4 v = make_float4(acc[i][0], acc[i][1], acc[i][2], acc[i][3]);
            *reinterpret_cast<float4*>(h1 + grow * F_IN + cg * 4) = v;
        }
    }
}

// ---------------- conv1 attention scores ----------------
__global__ void att1_kernel(const float* __restrict__ h1,
                            const float* __restrict__ att_src, const float* __restrict__ att_dst,
                            float* __restrict__ a_src, float* __restrict__ a_dst) {
    int idx = blockIdx.x * blockDim.x + threadIdx.x;   // node*8 + h
    if (idx >= N_NODES * NH1) return;
    int h = idx & 7;
    const float* hp = h1 + (size_t)(idx >> 3) * F_IN + h * ND1;
    float s1 = 0.f, s2 = 0.f;
    #pragma unroll
    for (int d = 0; d < ND1; ++d) {
        float v = hp[d];
        s1 = fmaf(v, att_src[h * ND1 + d], s1);
        s2 = fmaf(v, att_dst[h * ND1 + d], s2);
    }
    a_src[idx] = s1;
    a_dst[idx] = s2;
}

// ---------------- conv1 aggregation: one wave per dst node ----------------
__global__ __launch_bounds__(256) void agg1_kernel(const float* __restrict__ h1,
                                                   const float* __restrict__ a_src,
                                                   const float* __restrict__ a_dst,
                                                   const int* __restrict__ rowptr,
                                                   const int* __restrict__ esrc,
                                                   const float* __restrict__ b1,
                                                   float* __restrict__ hout) {
    int wid = (blockIdx.x * 256 + threadIdx.x) >> 6;   // node id (wave-uniform)
    if (wid >= N_NODES) return;
    int lane = threadIdx.x & 63;
    int ha = lane >> 4, hb = ha + 4;
    float adA = a_dst[wid * 8 + ha];
    float adB = a_dst[wid * 8 + hb];
    float accA = 0.f, accB = 0.f, denA = 0.f, denB = 0.f;
    int jend = rowptr[wid + 1];
    for (int j = rowptr[wid]; j < jend; ++j) {
        int s = esrc[j];
        float asA = a_src[s * 8 + ha];
        float asB = a_src[s * 8 + hb];
        float pA = __expf(lrelu(asA + adA));
        float pB = __expf(lrelu(asB + adB));
        denA += pA; denB += pB;
        accA = fmaf(pA, h1[(size_t)s * F_IN + lane], accA);
        accB = fmaf(pB, h1[(size_t)s * F_IN + 64 + lane], accB);
    }
    hout[(size_t)wid * F_IN + lane]      = elu1(accA / denA + b1[lane]);
    hout[(size_t)wid * F_IN + 64 + lane] = elu1(accB / denB + b1[64 + lane]);
}

// ---------------- conv2 GEMM + attention scores ----------------
__global__ __launch_bounds__(256) void gemm2_kernel(const float* __restrict__ h,
                                                    const float* __restrict__ W2,
                                                    const float* __restrict__ att_src2,
                                                    const float* __restrict__ att_dst2,
                                                    float* __restrict__ h2,
                                                    float* __restrict__ a_src2,
                                                    float* __restrict__ a_dst2) {
    __shared__ float Ws[F_IN * ND2];     // 4 KB
    __shared__ float Hs[32 * 132];       // padded, ~16.9 KB
    int t = threadIdx.x;
    int node0 = blockIdx.x * 32;
    #pragma unroll
    for (int i = 0; i < 4; ++i) { int idx = i * 256 + t; Ws[idx] = W2[idx]; }
    #pragma unroll
    for (int i = 0; i < 4; ++i) {
        int fidx = i * 256 + t;
        int r = fidx >> 5;
        int c4 = fidx & 31;
        int grow = node0 + r;
        float4 v = make_float4(0.f, 0.f, 0.f, 0.f);
        if (grow < N_NODES) v = *reinterpret_cast<const float4*>(h + (size_t)grow * F_IN + c4 * 4);
        *reinterpret_cast<float4*>(&Hs[r * 132 + c4 * 4]) = v;
    }
    __syncthreads();
    int nsub = t >> 3, d = t & 7;
    int node = node0 + nsub;
    float acc = 0.f;
    #pragma unroll 8
    for (int k = 0; k < F_IN; ++k)
        acc = fmaf(Hs[nsub * 132 + k], Ws[k * ND2 + d], acc);
    float vs = acc * att_src2[d];
    float vd = acc * att_dst2[d];
    #pragma unroll
    for (int off = 4; off >= 1; off >>= 1) {
        vs += __shfl_xor(vs, off, 8);
        vd += __shfl_xor(vd, off, 8);
    }
    if (node < N_NODES) {
        h2[node * ND2 + d] = acc;
        if (d == 0) { a_src2[node] = vs; a_dst2[node] = vd; }
    }
}

// ---------------- conv2 aggregation: one thread per node ----------------
__global__ void agg2_kernel(const float* __restrict__ h2,
                            const float* __restrict__ a_src2, const float* __restrict__ a_dst2,
                            const int* __restrict__ rowptr, const int* __restrict__ esrc,
                            const float* __restrict__ b2, float* __restrict__ g) {
    int n = blockIdx.x * blockDim.x + threadIdx.x;
    if (n >= N_NODES) return;
    float ad = a_dst2[n];
    float acc[8] = {0.f, 0.f, 0.f, 0.f, 0.f, 0.f, 0.f, 0.f};
    float den = 0.f;
    int jend = rowptr[n + 1];
    for (int j = rowptr[n]; j < jend; ++j) {
        int s = esrc[j];
        float p = __expf(lrelu(a_src2[s] + ad));
        den += p;
        float4 va = *reinterpret_cast<const float4*>(h2 + s * ND2);
        float4 vb = *reinterpret_cast<const float4*>(h2 + s * ND2 + 4);
        acc[0] = fmaf(p, va.x, acc[0]); acc[1] = fmaf(p, va.y, acc[1]);
        acc[2] = fmaf(p, va.z, acc[2]); acc[3] = fmaf(p, va.w, acc[3]);
        acc[4] = fmaf(p, vb.x, acc[4]); acc[5] = fmaf(p, vb.y, acc[5]);
        acc[6] = fmaf(p, vb.z, acc[6]); acc[7] = fmaf(p, vb.w, acc[7]);
    }
    float inv = 1.f / den;
    float4 o0 = make_float4(elu1(acc[0] * inv + b2[0]), elu1(acc[1] * inv + b2[1]),
                            elu1(acc[2] * inv + b2[2]), elu1(acc[3] * inv + b2[3]));
    float4 o1 = make_float4(elu1(acc[4] * inv + b2[4]), elu1(acc[5] * inv + b2[5]),
                            elu1(acc[6] * inv + b2[6]), elu1(acc[7] * inv + b2[7]));
    *reinterpret_cast<float4*>(g + n * ND2)     = o0;
    *reinterpret_cast<float4*>(g + n * ND2 + 4) = o1;
}

// ---------------- fc1 partial: z(400000) . fc1_w(400000x84) ----------------
__global__ __launch_bounds__(256) void fc1_kernel(const float* __restrict__ z,
                                                  const float* __restrict__ w,
                                                  float* __restrict__ part) {
    __shared__ float red[252];
    int t = threadIdx.x;
    if (t >= 252) return;
    int rsub = t / 84, j = t % 84;
    const int Z = N_NODES * ND2;   // 400000
    float acc = 0.f;
    for (int i0 = blockIdx.x * 12; i0 < Z; i0 += gridDim.x * 12) {
        #pragma unroll
        for (int u = 0; u < 4; ++u) {
            int i = i0 + u * 3 + rsub;
            if (i < Z) acc = fmaf(z[i], w[(size_t)i * 84 + j], acc);
        }
    }
    red[t] = acc;
    __syncthreads();
    if (t < 84) {
        float s = red[t] + red[t + 84] + red[t + 168];
        atomicAdd(&part[t], s);
    }
}

// ---------------- tail MLP + log_softmax ----------------
__global__ __launch_bounds__(128) void fctail_kernel(const float* __restrict__ part,
                                                     const float* __restrict__ fc1_b,
                                                     const float* __restrict__ fc2_w,
                                                     const float* __restrict__ fc2_b,
                                                     const float* __restrict__ fc3_w,
                                                     const float* __restrict__ fc3_b,
                                                     float* __restrict__ out) {
    __shared__ float z1[84];
    __shared__ float z2[24];
    int t = threadIdx.x;
    if (t < 84) z1[t] = elu1(part[t] + fc1_b[t]);
    __syncthreads();
    if (t < 24) {
        float a = fc2_b[t];
        for (int i = 0; i < 84; ++i) a = fmaf(z1[i], fc2_w[i * 24 + t], a);
        z2[t] = elu1(a);
    }
    __syncthreads();
    if (t == 0) {
        float z3[2];
        #pragma unroll
        for (int jj = 0; jj < 2; ++jj) {
            float a = fc3_b[jj];
            for (int i = 0; i < 24; ++i) a = fmaf(z2[i], fc3_w[i * 2 + jj], a);
            z3[jj] = a;
        }
        float m = fmaxf(z3[0], z3[1]);
        float l = m + logf(__expf(z3[0] - m) + __expf(z3[1] - m));
        out[0] = z3[0] - l;
        out[1] = z3[1] - l;
    }
}

extern "C" void kernel_launch(void* const* d_in, const int* in_sizes, int n_in,
                              void* d_out, int out_size, void* d_ws, size_t ws_size,
                              hipStream_t stream) {
    const float* x        = (const float*)d_in[0];
    const int*   ei       = (const int*)d_in[1];
    const float* W1       = (const float*)d_in[2];
    const float* att_src1 = (const float*)d_in[3];
    const float* att_dst1 = (const float*)d_in[4];
    const float* b1       = (const float*)d_in[5];
    const float* W2       = (const float*)d_in[6];
    const float* att_src2 = (const float*)d_in[7];
    const float* att_dst2 = (const float*)d_in[8];
    const float* b2       = (const float*)d_in[9];
    const float* fc1_w    = (const float*)d_in[10];
    const float* fc1_b    = (const float*)d_in[11];
    const float* fc2_w    = (const float*)d_in[12];
    const float* fc2_b    = (const float*)d_in[13];
    const float* fc3_w    = (const float*)d_in[14];
    const float* fc3_b    = (const float*)d_in[15];
    float* out = (float*)d_out;

    char* ws = (char*)d_ws;
    float* h1     = (float*)(ws + 0);                    // 25,600,000 B
    float* hbuf   = (float*)(ws + 25600000);             // 25,600,000 B
    float* a_src1 = (float*)(ws + 51200000);             // 1,600,000 B
    float* a_dst1 = (float*)(ws + 52800000);             // 1,600,000 B
    float* h2     = (float*)(ws + 54400000);             // 1,600,000 B
    float* a_src2 = (float*)(ws + 56000000);             // 200,000 B
    float* a_dst2 = (float*)(ws + 56200000);             // 200,000 B
    float* g      = (float*)(ws + 56400000);             // 1,600,000 B
    int*   counts = (int*)  (ws + 58000000);             // 200,000 B
    int*   rowptr = (int*)  (ws + 58200000);             // 200,004 B (padded)
    int*   cursor = (int*)  (ws + 58400192);             // 200,000 B
    int*   esrc   = (int*)  (ws + 58600192);             // 3,400,000 B
    float* part   = (float*)(ws + 62000192);             // 384 B
    int*   flag   = (int*)  (ws + 62000576);             // 4 B

    hipMemsetAsync(part, 0, 384, stream);

    detect_kernel<<<1, 64, 0, stream>>>(ei, flag);
    init_counts_kernel<<<(N_NODES + 255) / 256, 256, 0, stream>>>(counts);
    hist_kernel<<<(NE + 255) / 256, 256, 0, stream>>>(ei, flag, counts);
    scan_kernel<<<1, 1024, 0, stream>>>(counts, rowptr, cursor);
    fill_kernel<<<(NE + N_NODES + 255) / 256, 256, 0, stream>>>(ei, flag, cursor, esrc);

    gemm1_kernel<<<(N_NODES + 63) / 64, 256, 0, stream>>>(x, W1, h1);
    att1_kernel<<<(N_NODES * NH1 + 255) / 256, 256, 0, stream>>>(h1, att_src1, att_dst1, a_src1, a_dst1);
    agg1_kernel<<<(N_NODES + 3) / 4, 256, 0, stream>>>(h1, a_src1, a_dst1, rowptr, esrc, b1, hbuf);

    gemm2_kernel<<<(N_NODES + 31) / 32, 256, 0, stream>>>(hbuf, W2, att_src2, att_dst2, h2, a_src2, a_dst2);
    agg2_kernel<<<(N_NODES + 255) / 256, 256, 0, stream>>>(h2, a_src2, a_dst2, rowptr, esrc, b2, g);

    fc1_kernel<<<2048, 256, 0, stream>>>(g, fc1_w, part);
    fctail_kernel<<<1, 128, 0, stream>>>(part, fc1_b, fc2_w, fc2_b, fc3_w, fc3_b, out);
}

// Round 2
// 308.891 us; speedup vs baseline: 1.2023x; 1.2023x over previous
//
#include <hip/hip_runtime.h>
#include <math.h>

#define N_NODES 50000
#define F_IN 128
#define NE 800000
#define NH1 8
#define ND1 16
#define ND2 8
#define NEG 0.2f

__device__ __forceinline__ float lrelu(float v) { return v > 0.f ? v : NEG * v; }
__device__ __forceinline__ float elu1(float v)  { return v > 0.f ? v : (__expf(v) - 1.f); }

__device__ __forceinline__ unsigned short f2bf(float f) {
    union { float f; unsigned int i; } c; c.f = f;
    unsigned int u = c.i;
    return (unsigned short)((u + 0x7FFFu + ((u >> 16) & 1u)) >> 16);
}
__device__ __forceinline__ float bflo(unsigned int u) {
    union { unsigned int i; float f; } c; c.i = u << 16; return c.f;
}
__device__ __forceinline__ float bfhi(unsigned int u) {
    union { unsigned int i; float f; } c; c.i = u & 0xFFFF0000u; return c.f;
}

// ---------------- edge dtype detection (int32 vs int64) ----------------
__global__ void detect_kernel(const int* __restrict__ ei, int* __restrict__ flag) {
    if (blockIdx.x == 0 && threadIdx.x == 0) {
        int all0 = 1;
        for (int k = 0; k < 64; ++k) {
            if (ei[2 * k + 1] != 0) { all0 = 0; break; }
        }
        *flag = all0;   // 1 => data is int64 (high words zero), 0 => int32
    }
}

// ---------------- CSR build ----------------
__global__ void init_counts_kernel(int* __restrict__ counts) {
    int i = blockIdx.x * blockDim.x + threadIdx.x;
    if (i < N_NODES) counts[i] = 1;   // self-loop
}

__global__ void hist_kernel(const int* __restrict__ ei, const int* __restrict__ flag,
                            int* __restrict__ counts) {
    int e = blockIdx.x * blockDim.x + threadIdx.x;
    if (e >= NE) return;
    int is64 = *flag;
    int d = is64 ? ei[2 * NE + 2 * e] : ei[NE + e];
    atomicAdd(&counts[d], 1);
}

__global__ __launch_bounds__(1024) void scan_kernel(const int* __restrict__ counts,
                                                    int* __restrict__ rowptr,
                                                    int* __restrict__ cursor) {
    __shared__ int wsum[16];
    __shared__ int wpre[16];
    __shared__ int s_total;
    const int t = threadIdx.x;
    const int lane = t & 63, w = t >> 6;
    int carry = 0;
    if (t == 0) rowptr[0] = 0;
    for (int base = 0; base < N_NODES; base += 1024) {
        int i = base + t;
        int orig = (i < N_NODES) ? counts[i] : 0;
        int v = orig;
        #pragma unroll
        for (int off = 1; off < 64; off <<= 1) {
            int u = __shfl_up(v, off, 64);
            if (lane >= off) v += u;
        }
        if (lane == 63) wsum[w] = v;
        __syncthreads();
        if (t == 0) {
            int s = 0;
            #pragma unroll
            for (int j = 0; j < 16; ++j) { wpre[j] = s; s += wsum[j]; }
            s_total = s;
        }
        __syncthreads();
        int incl = v + wpre[w] + carry;
        if (i < N_NODES) { rowptr[i + 1] = incl; cursor[i] = incl - orig; }
        carry += s_total;
        __syncthreads();
    }
}

__global__ void fill_kernel(const int* __restrict__ ei, const int* __restrict__ flag,
                            int* __restrict__ cursor, int* __restrict__ esrc) {
    int i = blockIdx.x * blockDim.x + threadIdx.x;
    if (i >= NE + N_NODES) return;
    int is64 = *flag;
    int s, d;
    if (i < NE) {
        if (is64) { s = ei[2 * i]; d = ei[2 * NE + 2 * i]; }
        else      { s = ei[i];     d = ei[NE + i]; }
    } else {
        s = d = i - NE;
    }
    int slot = atomicAdd(&cursor[d], 1);
    esrc[slot] = s;
}

// ---------------- conv1 GEMM: h1 = x @ W1, fused attention scores, bf16 output ----------------
__global__ __launch_bounds__(256) void gemm1_kernel(const float* __restrict__ x,
                                                    const float* __restrict__ W,
                                                    const float* __restrict__ att_src,
                                                    const float* __restrict__ att_dst,
                                                    unsigned int* __restrict__ h1b,
                                                    float* __restrict__ a_src1,
                                                    float* __restrict__ a_dst1) {
    __shared__ float Ws[32 * 128];
    __shared__ float Xs[32 * 68];   // transposed x chunk, stride 68 (16B-aligned rows)
    const int t = threadIdx.x;
    const int cg = t & 31;          // col group -> cols cg*4..+3
    const int rg = t >> 5;          // row group -> rows rg*8..+7
    const int row0 = blockIdx.x * 64;

    float acc[8][4];
    #pragma unroll
    for (int i = 0; i < 8; ++i)
        #pragma unroll
        for (int j = 0; j < 4; ++j) acc[i][j] = 0.f;

    for (int kc = 0; kc < 4; ++kc) {
        // stage W chunk (32 x 128)
        #pragma unroll
        for (int i = 0; i < 4; ++i) {
            int fidx = i * 256 + t;
            const float4 wv = *reinterpret_cast<const float4*>(W + kc * 32 * 128 + fidx * 4);
            *reinterpret_cast<float4*>(&Ws[fidx * 4]) = wv;
        }
        // stage x chunk transposed: Xs[kk][r] = x[row0+r][kc*32+kk]
        {
            int r = t >> 2;
            int k4a = t & 3;
            int grow = row0 + r;
            #pragma unroll
            for (int p = 0; p < 2; ++p) {
                int k4 = k4a + p * 4;
                float4 xv = make_float4(0.f, 0.f, 0.f, 0.f);
                if (grow < N_NODES)
                    xv = *reinterpret_cast<const float4*>(x + grow * F_IN + kc * 32 + k4 * 4);
                Xs[(k4 * 4 + 0) * 68 + r] = xv.x;
                Xs[(k4 * 4 + 1) * 68 + r] = xv.y;
                Xs[(k4 * 4 + 2) * 68 + r] = xv.z;
                Xs[(k4 * 4 + 3) * 68 + r] = xv.w;
            }
        }
        __syncthreads();
        #pragma unroll
        for (int kk = 0; kk < 32; ++kk) {
            float4 wv = *reinterpret_cast<const float4*>(&Ws[kk * 128 + cg * 4]);
            float4 xa = *reinterpret_cast<const float4*>(&Xs[kk * 68 + rg * 8]);
            float4 xb = *reinterpret_cast<const float4*>(&Xs[kk * 68 + rg * 8 + 4]);
            float xr[8] = {xa.x, xa.y, xa.z, xa.w, xb.x, xb.y, xb.z, xb.w};
            float wr[4] = {wv.x, wv.y, wv.z, wv.w};
            #pragma unroll
            for (int i = 0; i < 8; ++i)
                #pragma unroll
                for (int j = 0; j < 4; ++j)
                    acc[i][j] = fmaf(xr[i], wr[j], acc[i][j]);
        }
        __syncthreads();
    }
    // epilogue: bf16 store + fused attention score partials
    const int h = cg >> 2;          // head 0..7
    const int q = cg & 3;           // quarter within head (dims 4q..4q+3)
    float as0 = att_src[h * ND1 + 4 * q + 0], as1 = att_src[h * ND1 + 4 * q + 1];
    float as2 = att_src[h * ND1 + 4 * q + 2], as3 = att_src[h * ND1 + 4 * q + 3];
    float ad0 = att_dst[h * ND1 + 4 * q + 0], ad1 = att_dst[h * ND1 + 4 * q + 1];
    float ad2 = att_dst[h * ND1 + 4 * q + 2], ad3 = att_dst[h * ND1 + 4 * q + 3];
    #pragma unroll
    for (int i = 0; i < 8; ++i) {
        int grow = row0 + rg * 8 + i;
        float ps = acc[i][0] * as0 + acc[i][1] * as1 + acc[i][2] * as2 + acc[i][3] * as3;
        float pd = acc[i][0] * ad0 + acc[i][1] * ad1 + acc[i][2] * ad2 + acc[i][3] * ad3;
        ps += __shfl_xor(ps, 1, 64); ps += __shfl_xor(ps, 2, 64);
        pd += __shfl_xor(pd, 1, 64); pd += __shfl_xor(pd, 2, 64);
        if (grow < N_NODES) {
            uint2 wv;
            wv.x = (unsigned int)f2bf(acc[i][0]) | ((unsigned int)f2bf(acc[i][1]) << 16);
            wv.y = (unsigned int)f2bf(acc[i][2]) | ((unsigned int)f2bf(acc[i][3]) << 16);
            *reinterpret_cast<uint2*>(h1b + (size_t)grow * 64 + cg * 2) = wv;
            if (q == 0) {
                a_src1[grow * 8 + h] = ps;
                a_dst1[grow * 8 + h] = pd;
            }
        }
    }
}

// ---------------- conv1 aggregation: one wave per dst node, bf16 gather ----------------
__global__ __launch_bounds__(256) void agg1_kernel(const unsigned int* __restrict__ h1b,
                                                   const float* __restrict__ a_src,
                                                   const float* __restrict__ a_dst,
                                                   const int* __restrict__ rowptr,
                                                   const int* __restrict__ esrc,
                                                   const float* __restrict__ b1,
                                                   float* __restrict__ hout) {
    int wid = (blockIdx.x * 256 + threadIdx.x) >> 6;   // node id (wave-uniform)
    if (wid >= N_NODES) return;
    const int lane = threadIdx.x & 63;
    const int h = lane >> 3;                            // head for this lane's 2 dims
    const float ad = a_dst[wid * 8 + h];
    float acc0 = 0.f, acc1 = 0.f, den = 0.f;
    int j = rowptr[wid];
    const int jend = rowptr[wid + 1];
    for (; j + 4 <= jend; j += 4) {
        int s0 = esrc[j], s1 = esrc[j + 1], s2 = esrc[j + 2], s3 = esrc[j + 3];
        float e0 = a_src[s0 * 8 + h], e1 = a_src[s1 * 8 + h];
        float e2 = a_src[s2 * 8 + h], e3 = a_src[s3 * 8 + h];
        unsigned int u0 = h1b[(size_t)s0 * 64 + lane];
        unsigned int u1 = h1b[(size_t)s1 * 64 + lane];
        unsigned int u2 = h1b[(size_t)s2 * 64 + lane];
        unsigned int u3 = h1b[(size_t)s3 * 64 + lane];
        float p0 = __expf(lrelu(e0 + ad));
        float p1 = __expf(lrelu(e1 + ad));
        float p2 = __expf(lrelu(e2 + ad));
        float p3 = __expf(lrelu(e3 + ad));
        den += (p0 + p1) + (p2 + p3);
        acc0 = fmaf(p0, bflo(u0), acc0); acc1 = fmaf(p0, bfhi(u0), acc1);
        acc0 = fmaf(p1, bflo(u1), acc0); acc1 = fmaf(p1, bfhi(u1), acc1);
        acc0 = fmaf(p2, bflo(u2), acc0); acc1 = fmaf(p2, bfhi(u2), acc1);
        acc0 = fmaf(p3, bflo(u3), acc0); acc1 = fmaf(p3, bfhi(u3), acc1);
    }
    for (; j < jend; ++j) {
        int s = esrc[j];
        float e = a_src[s * 8 + h];
        unsigned int u = h1b[(size_t)s * 64 + lane];
        float p = __expf(lrelu(e + ad));
        den += p;
        acc0 = fmaf(p, bflo(u), acc0);
        acc1 = fmaf(p, bfhi(u), acc1);
    }
    float inv = 1.f / den;
    float2 bb = *reinterpret_cast<const float2*>(b1 + 2 * lane);
    float o0 = elu1(acc0 * inv + bb.x);
    float o1 = elu1(acc1 * inv + bb.y);
    *reinterpret_cast<float2*>(hout + (size_t)wid * F_IN + 2 * lane) = make_float2(o0, o1);
}

// ---------------- conv2 GEMM + attention scores ----------------
__global__ __launch_bounds__(256) void gemm2_kernel(const float* __restrict__ h,
                                                    const float* __restrict__ W2,
                                                    const float* __restrict__ att_src2,
                                                    const float* __restrict__ att_dst2,
                                                    float* __restrict__ h2,
                                                    float* __restrict__ a_src2,
                                                    float* __restrict__ a_dst2) {
    __shared__ float Ws[F_IN * ND2];     // 4 KB
    __shared__ float Hs[32 * 132];       // padded, ~16.9 KB
    int t = threadIdx.x;
    int node0 = blockIdx.x * 32;
    #pragma unroll
    for (int i = 0; i < 4; ++i) { int idx = i * 256 + t; Ws[idx] = W2[idx]; }
    #pragma unroll
    for (int i = 0; i < 4; ++i) {
        int fidx = i * 256 + t;
        int r = fidx >> 5;
        int c4 = fidx & 31;
        int grow = node0 + r;
        float4 v = make_float4(0.f, 0.f, 0.f, 0.f);
        if (grow < N_NODES) v = *reinterpret_cast<const float4*>(h + (size_t)grow * F_IN + c4 * 4);
        *reinterpret_cast<float4*>(&Hs[r * 132 + c4 * 4]) = v;
    }
    __syncthreads();
    int nsub = t >> 3, d = t & 7;
    int node = node0 + nsub;
    float acc = 0.f;
    #pragma unroll 8
    for (int k = 0; k < F_IN; ++k)
        acc = fmaf(Hs[nsub * 132 + k], Ws[k * ND2 + d], acc);
    float vs = acc * att_src2[d];
    float vd = acc * att_dst2[d];
    #pragma unroll
    for (int off = 4; off >= 1; off >>= 1) {
        vs += __shfl_xor(vs, off, 8);
        vd += __shfl_xor(vd, off, 8);
    }
    if (node < N_NODES) {
        h2[node * ND2 + d] = acc;
        if (d == 0) { a_src2[node] = vs; a_dst2[node] = vd; }
    }
}

// ---------------- conv2 aggregation: one thread per node ----------------
__global__ void agg2_kernel(const float* __restrict__ h2,
                            const float* __restrict__ a_src2, const float* __restrict__ a_dst2,
                            const int* __restrict__ rowptr, const int* __restrict__ esrc,
                            const float* __restrict__ b2, float* __restrict__ g) {
    int n = blockIdx.x * blockDim.x + threadIdx.x;
    if (n >= N_NODES) return;
    float ad = a_dst2[n];
    float acc[8] = {0.f, 0.f, 0.f, 0.f, 0.f, 0.f, 0.f, 0.f};
    float den = 0.f;
    int jend = rowptr[n + 1];
    for (int j = rowptr[n]; j < jend; ++j) {
        int s = esrc[j];
        float p = __expf(lrelu(a_src2[s] + ad));
        den += p;
        float4 va = *reinterpret_cast<const float4*>(h2 + s * ND2);
        float4 vb = *reinterpret_cast<const float4*>(h2 + s * ND2 + 4);
        acc[0] = fmaf(p, va.x, acc[0]); acc[1] = fmaf(p, va.y, acc[1]);
        acc[2] = fmaf(p, va.z, acc[2]); acc[3] = fmaf(p, va.w, acc[3]);
        acc[4] = fmaf(p, vb.x, acc[4]); acc[5] = fmaf(p, vb.y, acc[5]);
        acc[6] = fmaf(p, vb.z, acc[6]); acc[7] = fmaf(p, vb.w, acc[7]);
    }
    float inv = 1.f / den;
    float4 o0 = make_float4(elu1(acc[0] * inv + b2[0]), elu1(acc[1] * inv + b2[1]),
                            elu1(acc[2] * inv + b2[2]), elu1(acc[3] * inv + b2[3]));
    float4 o1 = make_float4(elu1(acc[4] * inv + b2[4]), elu1(acc[5] * inv + b2[5]),
                            elu1(acc[6] * inv + b2[6]), elu1(acc[7] * inv + b2[7]));
    *reinterpret_cast<float4*>(g + n * ND2)     = o0;
    *reinterpret_cast<float4*>(g + n * ND2 + 4) = o1;
}

// ---------------- fc1 partial: z(400000) . fc1_w(400000x84) ----------------
__global__ __launch_bounds__(256) void fc1_kernel(const float* __restrict__ z,
                                                  const float* __restrict__ w,
                                                  float* __restrict__ part) {
    __shared__ float red[252];
    int t = threadIdx.x;
    if (t >= 252) return;
    int rsub = t / 84, j = t % 84;
    const int Z = N_NODES * ND2;   // 400000
    float acc = 0.f;
    for (int i0 = blockIdx.x * 12; i0 < Z; i0 += gridDim.x * 12) {
        #pragma unroll
        for (int u = 0; u < 4; ++u) {
            int i = i0 + u * 3 + rsub;
            if (i < Z) acc = fmaf(z[i], w[(size_t)i * 84 + j], acc);
        }
    }
    red[t] = acc;
    __syncthreads();
    if (t < 84) {
        float s = red[t] + red[t + 84] + red[t + 168];
        atomicAdd(&part[t], s);
    }
}

// ---------------- tail MLP + log_softmax ----------------
__global__ __launch_bounds__(128) void fctail_kernel(const float* __restrict__ part,
                                                     const float* __restrict__ fc1_b,
                                                     const float* __restrict__ fc2_w,
                                                     const float* __restrict__ fc2_b,
                                                     const float* __restrict__ fc3_w,
                                                     const float* __restrict__ fc3_b,
                                                     float* __restrict__ out) {
    __shared__ float z1[84];
    __shared__ float z2[24];
    int t = threadIdx.x;
    if (t < 84) z1[t] = elu1(part[t] + fc1_b[t]);
    __syncthreads();
    if (t < 24) {
        float a = fc2_b[t];
        for (int i = 0; i < 84; ++i) a = fmaf(z1[i], fc2_w[i * 24 + t], a);
        z2[t] = elu1(a);
    }
    __syncthreads();
    if (t == 0) {
        float z3[2];
        #pragma unroll
        for (int jj = 0; jj < 2; ++jj) {
            float a = fc3_b[jj];
            for (int i = 0; i < 24; ++i) a = fmaf(z2[i], fc3_w[i * 2 + jj], a);
            z3[jj] = a;
        }
        float m = fmaxf(z3[0], z3[1]);
        float l = m + logf(__expf(z3[0] - m) + __expf(z3[1] - m));
        out[0] = z3[0] - l;
        out[1] = z3[1] - l;
    }
}

extern "C" void kernel_launch(void* const* d_in, const int* in_sizes, int n_in,
                              void* d_out, int out_size, void* d_ws, size_t ws_size,
                              hipStream_t stream) {
    const float* x        = (const float*)d_in[0];
    const int*   ei       = (const int*)d_in[1];
    const float* W1       = (const float*)d_in[2];
    const float* att_src1 = (const float*)d_in[3];
    const float* att_dst1 = (const float*)d_in[4];
    const float* b1       = (const float*)d_in[5];
    const float* W2       = (const float*)d_in[6];
    const float* att_src2 = (const float*)d_in[7];
    const float* att_dst2 = (const float*)d_in[8];
    const float* b2       = (const float*)d_in[9];
    const float* fc1_w    = (const float*)d_in[10];
    const float* fc1_b    = (const float*)d_in[11];
    const float* fc2_w    = (const float*)d_in[12];
    const float* fc2_b    = (const float*)d_in[13];
    const float* fc3_w    = (const float*)d_in[14];
    const float* fc3_b    = (const float*)d_in[15];
    float* out = (float*)d_out;

    char* ws = (char*)d_ws;
    unsigned int* h1b = (unsigned int*)(ws + 0);         // 12,800,000 B
    float* hbuf   = (float*)(ws + 12800000);             // 25,600,000 B
    float* a_src1 = (float*)(ws + 38400000);             // 1,600,000 B
    float* a_dst1 = (float*)(ws + 40000000);             // 1,600,000 B
    float* h2     = (float*)(ws + 41600000);             // 1,600,000 B
    float* a_src2 = (float*)(ws + 43200000);             // 200,000 B
    float* a_dst2 = (float*)(ws + 43400000);             // 200,000 B
    float* g      = (float*)(ws + 43600000);             // 1,600,000 B
    int*   counts = (int*)  (ws + 45200000);             // 200,000 B
    int*   rowptr = (int*)  (ws + 45400000);             // 200,004 B (padded)
    int*   cursor = (int*)  (ws + 45600192);             // 200,000 B
    int*   esrc   = (int*)  (ws + 45800192);             // 3,400,000 B
    float* part   = (float*)(ws + 49200192);             // 384 B
    int*   flag   = (int*)  (ws + 49200576);             // 4 B

    hipMemsetAsync(part, 0, 384, stream);

    detect_kernel<<<1, 64, 0, stream>>>(ei, flag);
    init_counts_kernel<<<(N_NODES + 255) / 256, 256, 0, stream>>>(counts);
    hist_kernel<<<(NE + 255) / 256, 256, 0, stream>>>(ei, flag, counts);
    scan_kernel<<<1, 1024, 0, stream>>>(counts, rowptr, cursor);
    fill_kernel<<<(NE + N_NODES + 255) / 256, 256, 0, stream>>>(ei, flag, cursor, esrc);

    gemm1_kernel<<<(N_NODES + 63) / 64, 256, 0, stream>>>(x, W1, att_src1, att_dst1, h1b, a_src1, a_dst1);
    agg1_kernel<<<(N_NODES + 3) / 4, 256, 0, stream>>>(h1b, a_src1, a_dst1, rowptr, esrc, b1, hbuf);

    gemm2_kernel<<<(N_NODES + 31) / 32, 256, 0, stream>>>(hbuf, W2, att_src2, att_dst2, h2, a_src2, a_dst2);
    agg2_kernel<<<(N_NODES + 255) / 256, 256, 0, stream>>>(h2, a_src2, a_dst2, rowptr, esrc, b2, g);

    fc1_kernel<<<2048, 256, 0, stream>>>(g, fc1_w, part);
    fctail_kernel<<<1, 128, 0, stream>>>(part, fc1_b, fc2_w, fc2_b, fc3_w, fc3_b, out);
}